// Round 1
// baseline (426.024 us; speedup 1.0000x reference)
//
#include <hip/hip_runtime.h>
#include <hip/hip_bf16.h>
#include <math.h>

typedef __bf16 bf16_t;
typedef __bf16 bf16x8 __attribute__((ext_vector_type(8)));
typedef __bf16 bf16x2 __attribute__((ext_vector_type(2)));
typedef float  f32x4  __attribute__((ext_vector_type(4)));

#define MINST 50000

__device__ __forceinline__ float fast_sigmoid(float x){
  return __fdividef(1.f, 1.f + __expf(-x));
}
__device__ __forceinline__ float fast_tanh(float x){
  float e = __expf(2.f*x);
  return 1.f - __fdividef(2.f, e + 1.f);
}

// ---------- prep: W[1024][512] -> WT[512][1024] bf16 ----------
__global__ void prep_wt(const float* __restrict__ W, bf16_t* __restrict__ WT){
  int idx = blockIdx.x*256 + threadIdx.x;         // 512*1024 elements
  if (idx >= 512*1024) return;
  int n = idx >> 10, k = idx & 1023;
  WT[idx] = (bf16_t)W[k*512 + n];
}

// ---------- prep: Ua/Ub[4][512][256] -> UabT[2048][512] bf16, cols interleaved (2t=a, 2t+1=b) ----------
__global__ void prep_uab(const float* __restrict__ Ua, const float* __restrict__ Ub,
                         bf16_t* __restrict__ UabT){
  int idx = blockIdx.x*256 + threadIdx.x;         // 2048*512 elements
  if (idx >= 2048*512) return;
  int c = idx >> 9, k = idx & 511;
  int s = c & 1, t = c >> 1;
  int n = t >> 8, l = t & 255;
  const float* src = s ? Ub : Ua;
  UabT[idx] = (bf16_t)src[(n*512 + k)*256 + l];
}

__global__ void zero_ws_k(float* __restrict__ Alogit, float* __restrict__ Mbuf){
  int i = blockIdx.x*256 + threadIdx.x;
  if (i < MINST) Alogit[i] = 0.f;
  if (i < 513)   Mbuf[i]  = 0.f;
}

// ---------- MFMA GEMM, 128x128 tile, BK=32, 4 waves (2x2), padded LDS ----------
// EPI=0: A is f32 (h), epilogue relu+bias -> bf16 Xout.   EPI=1: A is bf16 (Xb), attention epilogue.
template<int EPI, int K>
__global__ __launch_bounds__(256, 2)
void gemm_k(const void* __restrict__ Ap, const bf16_t* __restrict__ Bp, int M,
            const float* __restrict__ bias, bf16_t* __restrict__ Xout,
            const float* __restrict__ Uc, float* __restrict__ Alogit)
{
  __shared__ bf16_t As[128*40] __attribute__((aligned(16)));
  __shared__ bf16_t Bs[128*40] __attribute__((aligned(16)));
  const int tid  = threadIdx.x;
  const int lane = tid & 63;
  const int wid  = tid >> 6;
  const int wr   = wid >> 1;
  const int wc   = wid & 1;
  const int m0   = blockIdx.x * 128;
  const int n0   = blockIdx.y * 128;

  const f32x4 fzero = {0.f, 0.f, 0.f, 0.f};
  f32x4 acc[4][4];
#pragma unroll
  for (int m = 0; m < 4; ++m)
#pragma unroll
    for (int n = 0; n < 4; ++n) acc[m][n] = fzero;

  const int q_row  = tid >> 2;          // chunk row (first half), 0..63
  const int q_c    = tid & 3;           // 16B chunk in k-dim
  const int a_row  = tid >> 1;          // f32 path row 0..127
  const int a_half = tid & 1;

  bf16x8 sB0, sB1, sA0, sA1;
  f32x4  sAf[4];

  auto loadTiles = [&](int k0){
    sB0 = *(const bf16x8*)(Bp + (size_t)(n0 + q_row     )*K + k0 + q_c*8);
    sB1 = *(const bf16x8*)(Bp + (size_t)(n0 + q_row + 64)*K + k0 + q_c*8);
    if constexpr (EPI == 0) {
      const float* A = (const float*)Ap;
      int gr = m0 + a_row;
      if (gr < M) {
        const f32x4* p = (const f32x4*)(A + (size_t)gr*K + k0 + a_half*16);
        sAf[0]=p[0]; sAf[1]=p[1]; sAf[2]=p[2]; sAf[3]=p[3];
      } else {
        sAf[0]=fzero; sAf[1]=fzero; sAf[2]=fzero; sAf[3]=fzero;
      }
    } else {
      const bf16_t* A = (const bf16_t*)Ap;
      int g0 = m0 + q_row, g1 = m0 + q_row + 64;
      bf16x8 z;
#pragma unroll
      for (int j = 0; j < 8; ++j) z[j] = (bf16_t)0.f;
      sA0 = (g0 < M) ? *(const bf16x8*)(A + (size_t)g0*K + k0 + q_c*8) : z;
      sA1 = (g1 < M) ? *(const bf16x8*)(A + (size_t)g1*K + k0 + q_c*8) : z;
    }
  };

  auto storeTiles = [&](){
    *(bf16x8*)&Bs[(q_row     )*40 + q_c*8] = sB0;
    *(bf16x8*)&Bs[(q_row + 64)*40 + q_c*8] = sB1;
    if constexpr (EPI == 0) {
      bf16x8 lo, hi;
#pragma unroll
      for (int j = 0; j < 4; ++j) {
        lo[j]   = (bf16_t)sAf[0][j];
        lo[4+j] = (bf16_t)sAf[1][j];
        hi[j]   = (bf16_t)sAf[2][j];
        hi[4+j] = (bf16_t)sAf[3][j];
      }
      *(bf16x8*)&As[a_row*40 + a_half*16    ] = lo;
      *(bf16x8*)&As[a_row*40 + a_half*16 + 8] = hi;
    } else {
      *(bf16x8*)&As[(q_row     )*40 + q_c*8] = sA0;
      *(bf16x8*)&As[(q_row + 64)*40 + q_c*8] = sA1;
    }
  };

  loadTiles(0);
  const int fr = lane & 15;
  const int kh = lane >> 4;
  constexpr int NT = K / 32;
  for (int kt = 0; kt < NT; ++kt) {
    __syncthreads();
    storeTiles();
    __syncthreads();
    if (kt + 1 < NT) loadTiles((kt+1)*32);
    bf16x8 a[4], b[4];
#pragma unroll
    for (int m = 0; m < 4; ++m)
      a[m] = *(const bf16x8*)&As[(wr*64 + m*16 + fr)*40 + kh*8];
#pragma unroll
    for (int n = 0; n < 4; ++n)
      b[n] = *(const bf16x8*)&Bs[(wc*64 + n*16 + fr)*40 + kh*8];
#pragma unroll
    for (int m = 0; m < 4; ++m)
#pragma unroll
      for (int n = 0; n < 4; ++n)
        acc[m][n] = __builtin_amdgcn_mfma_f32_16x16x32_bf16(a[m], b[n], acc[m][n], 0, 0, 0);
  }

  const int rg = lane >> 4;
  if constexpr (EPI == 0) {
#pragma unroll
    for (int n = 0; n < 4; ++n) {
      int col = n0 + wc*64 + n*16 + fr;
      float bv = bias[col];
#pragma unroll
      for (int m = 0; m < 4; ++m)
#pragma unroll
        for (int r = 0; r < 4; ++r) {
          int row = m0 + wr*64 + m*16 + rg*4 + r;
          if (row < M) {
            float v = acc[m][n][r] + bv;
            Xout[(size_t)row*512 + col] = (bf16_t)(v > 0.f ? v : 0.f);
          }
        }
    }
  } else {
    float gacc[4][4];
#pragma unroll
    for (int m = 0; m < 4; ++m)
#pragma unroll
      for (int r = 0; r < 4; ++r) gacc[m][r] = 0.f;
    const bool even = (lane & 1) == 0;
#pragma unroll
    for (int n = 0; n < 4; ++n) {
      int col = n0 + wc*64 + n*16 + fr;
      float ucv = Uc[col >> 1];    // pair index; valid on even lanes
#pragma unroll
      for (int m = 0; m < 4; ++m)
#pragma unroll
        for (int r = 0; r < 4; ++r) {
          float v = acc[m][n][r];
          float p = __shfl_xor(v, 1);
          float g = even ? fast_tanh(v) * fast_sigmoid(p) * ucv : 0.f;
          gacc[m][r] += g;
        }
    }
#pragma unroll
    for (int m = 0; m < 4; ++m)
#pragma unroll
      for (int r = 0; r < 4; ++r) {
        float s = gacc[m][r];
        s += __shfl_xor(s, 1);
        s += __shfl_xor(s, 2);
        s += __shfl_xor(s, 4);
        s += __shfl_xor(s, 8);
        if (fr == 0) {
          int row = m0 + wr*64 + m*16 + rg*4 + r;
          if (row < M) atomicAdd(&Alogit[row], s);
        }
      }
  }
}

// ---------- A = sigmoid(Alogit); write to out; accumulate sumA ----------
__global__ void a_final(const float* __restrict__ Alogit, float* __restrict__ outA,
                        float* __restrict__ sumA){
  int i = blockIdx.x*256 + threadIdx.x;
  float a = 0.f;
  if (i < MINST) { a = fast_sigmoid(Alogit[i]); outA[i] = a; }
  float s = a;
#pragma unroll
  for (int o = 1; o < 64; o <<= 1) s += __shfl_xor(s, o);
  __shared__ float wsum[4];
  int lane = threadIdx.x & 63, w = threadIdx.x >> 6;
  if (lane == 0) wsum[w] = s;
  __syncthreads();
  if (threadIdx.x == 0) atomicAdd(sumA, wsum[0]+wsum[1]+wsum[2]+wsum[3]);
}

// ---------- M[512] = sum_i A_i * x_i ----------
__global__ void m_reduce(const bf16_t* __restrict__ Xb, const float* __restrict__ Aout,
                         float* __restrict__ Mbuf){
  int t = threadIdx.x;     // 256 threads, 2 cols each
  int c0 = t*2;
  float acc0 = 0.f, acc1 = 0.f;
  for (int r = blockIdx.x; r < MINST; r += gridDim.x) {
    float a = Aout[r];
    bf16x2 x = *(const bf16x2*)(Xb + (size_t)r*512 + c0);
    acc0 += a * (float)x[0];
    acc1 += a * (float)x[1];
  }
  atomicAdd(&Mbuf[c0],   acc0);
  atomicAdd(&Mbuf[c0+1], acc1);
}

__device__ __forceinline__ float block_sum256(float v, float* red){
  int t = threadIdx.x;
  red[t] = v; __syncthreads();
  for (int s = 128; s > 0; s >>= 1) {
    if (t < s) red[t] += red[t+s];
    __syncthreads();
  }
  float r = red[0];
  __syncthreads();
  return r;
}

// ---------- VQ + classifier tail, single block ----------
__global__ __launch_bounds__(256)
void finalize_k(const float* __restrict__ Mbuf, const float* __restrict__ cb,
                const float* __restrict__ clsW, const float* __restrict__ clsb,
                float* __restrict__ dout)
{
  __shared__ float Mn[512];
  __shared__ float red[256];
  __shared__ float dist[256];
  __shared__ int   idxs[256];
  __shared__ int   indS;
  int t = threadIdx.x;
  float sA = Mbuf[512];
  Mn[t]     = Mbuf[t]     / sA;
  Mn[t+256] = Mbuf[t+256] / sA;
  __syncthreads();
  float msq_p = Mn[t]*Mn[t] + Mn[t+256]*Mn[t+256];
  float Msq = block_sum256(msq_p, red);

  const float* cbr = cb + t*512;
  float cs = 0.f, dt = 0.f;
  for (int k = 0; k < 512; k += 4) {
    f32x4 c = *(const f32x4*)(cbr + k);
    cs += c[0]*c[0] + c[1]*c[1] + c[2]*c[2] + c[3]*c[3];
    dt += Mn[k]*c[0] + Mn[k+1]*c[1] + Mn[k+2]*c[2] + Mn[k+3]*c[3];
  }
  // faithful to reference (sign bug kept): dist = |M|^2 + |cb|^2 + 2*M.cb
  dist[t] = Msq + cs + 2.f*dt;
  idxs[t] = t;
  __syncthreads();
  for (int s = 128; s > 0; s >>= 1) {
    if (t < s && dist[t+s] < dist[t]) { dist[t] = dist[t+s]; idxs[t] = idxs[t+s]; }
    __syncthreads();
  }
  if (t == 0) indS = idxs[0];
  __syncthreads();

  const float* q = cb + (size_t)indS*512;
  float d0 = q[t]     - Mn[t];
  float d1 = q[t+256] - Mn[t+256];
  float vqs = block_sum256(d0*d0 + d1*d1, red);
  float vq_loss = 1.25f * (vqs / 512.f);   // (BETA+1) * mean((q-M)^2)

  float p0 = Mn[t]*clsW[t*2]   + Mn[t+256]*clsW[(t+256)*2];
  float p1 = Mn[t]*clsW[t*2+1] + Mn[t+256]*clsW[(t+256)*2+1];
  float l0 = block_sum256(p0, red);
  float l1 = block_sum256(p1, red);

  if (t == 0) {
    l0 += clsb[0]; l1 += clsb[1];
    float mx = fmaxf(l0, l1);
    float e0 = __expf(l0 - mx), e1 = __expf(l1 - mx);
    float si = e0 + e1;
    float y0 = e0 / si, y1 = e1 / si;
    int yhat = (l1 > l0) ? 1 : 0;    // first-max tie-break like argmax
    dout[0] = l0; dout[1] = l1;      // top_instance == logits (top_k over len-1)
    dout[2] = y0; dout[3] = y1;      // Y_prob
    dout[4] = (float)yhat;           // Y_hat
    dout[5] = vq_loss;
    dout[6] = y0; dout[7] = y1;      // y_probs
  }
}

extern "C" void kernel_launch(void* const* d_in, const int* in_sizes, int n_in,
                              void* d_out, int out_size, void* d_ws, size_t ws_size,
                              hipStream_t stream) {
  const float* h    = (const float*)d_in[0];
  const float* fcW  = (const float*)d_in[1];
  const float* fcb  = (const float*)d_in[2];
  const float* Ua   = (const float*)d_in[3];
  const float* Ub   = (const float*)d_in[4];
  const float* Uc   = (const float*)d_in[5];
  const float* clsW = (const float*)d_in[6];
  const float* clsb = (const float*)d_in[7];
  const float* cbk  = (const float*)d_in[8];
  float* out = (float*)d_out;

  char* ws = (char*)d_ws;
  bf16_t* Xb     = (bf16_t*)ws;                       // 50000*512*2  = 51,200,000 B
  bf16_t* WT     = (bf16_t*)(ws + 51200000);          // 512*1024*2   =  1,048,576 B
  bf16_t* UabT   = (bf16_t*)(ws + 52248576);          // 2048*512*2   =  2,097,152 B
  float*  Alogit = (float*)(ws + 54345728);           // 50000*4      =    200,000 B
  float*  Mbuf   = (float*)(ws + 54545728);           // 513*4 (M[512] + sumA)

  const int M = MINST;

  prep_wt <<<2048, 256, 0, stream>>>(fcW, WT);
  prep_uab<<<4096, 256, 0, stream>>>(Ua, Ub, UabT);
  zero_ws_k<<<196, 256, 0, stream>>>(Alogit, Mbuf);

  // fc + relu: x = relu(h @ W + b), bf16 out
  gemm_k<0,1024><<<dim3(391, 4), 256, 0, stream>>>(h, WT, M, fcb, Xb, nullptr, nullptr);
  // attention: pre = x @ [Ua|Ub interleaved]; Alogit += sum tanh(a)*sig(b)*Uc
  gemm_k<1, 512><<<dim3(391,16), 256, 0, stream>>>(Xb, UabT, M, nullptr, nullptr, Uc, Alogit);

  a_final <<<196, 256, 0, stream>>>(Alogit, out + 8, Mbuf + 512);
  m_reduce<<<256, 256, 0, stream>>>(Xb, out + 8, Mbuf);
  finalize_k<<<1, 256, 0, stream>>>(Mbuf, cbk, clsW, clsb, out);
}